// Round 1
// 187.409 us; speedup vs baseline: 1.0609x; 1.0609x over previous
//
#include <hip/hip_runtime.h>
#include <stdint.h>

// Problem constants (input: float32 (16, 37, 224, 224), label = 1)
#define NB 16
#define NC 37
#define H 224
#define W 224
#define HW (H * W)                     // 50176
#define WPR 7                          // 32-bit mask words per row (224 = 7*32)
#define IMG_WORDS (H * WPR)            // 1568
#define QUADS_PER_IMG (HW / 4)         // 12544
#define ABLK 64                        // threads per block for k_argmax/k_mask
#define BLOCKS_PER_IMG (QUADS_PER_IMG / ABLK)  // 196
#define REPS 16                        // fill replicas per image
#define OUT_Q4_PER_IMG (3 * H * (W / 4))       // 37632 float4 per image
#define OUT_Q4_PER_REP (OUT_Q4_PER_IMG / REPS) // 2352

typedef float f4 __attribute__((ext_vector_type(4)));

// ---------------------------------------------------------------------------
// K1: channel argmax (first-max tie-break == jnp.argmax). 64-thread blocks:
// 3136 blocks are ALL co-resident on 256 CUs (no block-scheduling tail on a
// memory-bound kernel). Block max via pure wave shfl reduce — no LDS, no
// barriers.
// ---------------------------------------------------------------------------
__global__ __launch_bounds__(64) void k_argmax(const float* __restrict__ in,
                                               uint8_t* __restrict__ lab,
                                               int* __restrict__ bmax) {
    const int qid = blockIdx.x * ABLK + threadIdx.x;
    const int b = blockIdx.x / BLOCKS_PER_IMG;
    const int p = (qid % QUADS_PER_IMG) * 4;
    const float4* base = (const float4*)(in + (size_t)b * NC * HW + p);
    float4 bv = base[0];
    int ix = 0, iy = 0, iz = 0, iw = 0;
#pragma unroll
    for (int c = 1; c < NC; c += 4) {
        float4 a0 = base[(size_t)(c + 0) * (HW / 4)];
        float4 a1 = base[(size_t)(c + 1) * (HW / 4)];
        float4 a2 = base[(size_t)(c + 2) * (HW / 4)];
        float4 a3 = base[(size_t)(c + 3) * (HW / 4)];
        if (a0.x > bv.x) { bv.x = a0.x; ix = c; }
        if (a0.y > bv.y) { bv.y = a0.y; iy = c; }
        if (a0.z > bv.z) { bv.z = a0.z; iz = c; }
        if (a0.w > bv.w) { bv.w = a0.w; iw = c; }
        if (a1.x > bv.x) { bv.x = a1.x; ix = c + 1; }
        if (a1.y > bv.y) { bv.y = a1.y; iy = c + 1; }
        if (a1.z > bv.z) { bv.z = a1.z; iz = c + 1; }
        if (a1.w > bv.w) { bv.w = a1.w; iw = c + 1; }
        if (a2.x > bv.x) { bv.x = a2.x; ix = c + 2; }
        if (a2.y > bv.y) { bv.y = a2.y; iy = c + 2; }
        if (a2.z > bv.z) { bv.z = a2.z; iz = c + 2; }
        if (a2.w > bv.w) { bv.w = a2.w; iw = c + 2; }
        if (a3.x > bv.x) { bv.x = a3.x; ix = c + 3; }
        if (a3.y > bv.y) { bv.y = a3.y; iy = c + 3; }
        if (a3.z > bv.z) { bv.z = a3.z; iz = c + 3; }
        if (a3.w > bv.w) { bv.w = a3.w; iw = c + 3; }
    }
    uint32_t packed = (uint32_t)ix | ((uint32_t)iy << 8) |
                      ((uint32_t)iz << 16) | ((uint32_t)iw << 24);
    *(uint32_t*)(lab + (size_t)b * HW + p) = packed;

    int mymax = max(max(ix, iy), max(iz, iw));
#pragma unroll
    for (int off = 32; off; off >>= 1) mymax = max(mymax, __shfl_xor(mymax, off));
    if (threadIdx.x == 0) bmax[blockIdx.x] = mymax;
}

// ---------------------------------------------------------------------------
// K2: quantize (37-entry LUT, bit-identical float op sequence) + exact
// integer 5x5 blur (S = sum k_i k_j q), threshold S >= 129
// (== round-half-even(S/256) > 0). 64-thread blocks; the per-image max is
// reduced from bmax[] entirely in-register (wave reduce), one barrier total.
// ---------------------------------------------------------------------------
__global__ __launch_bounds__(64) void k_mask(const uint8_t* __restrict__ lab,
                                             const int* __restrict__ bmax,
                                             uint32_t* __restrict__ mbits) {
    __shared__ int qlut[NC];
    const int tid = threadIdx.x;
    const int b = blockIdx.x / BLOCKS_PER_IMG;

    int m = 0;
    for (int i = tid; i < BLOCKS_PER_IMG; i += ABLK)
        m = max(m, bmax[b * BLOCKS_PER_IMG + i]);
#pragma unroll
    for (int off = 32; off; off >>= 1) m = max(m, __shfl_xor(m, off));
    if (tid < NC) {
        // identical op order to reference: floor(255.0f * (l / maxv))
        qlut[tid] = (m > 0) ? (int)floorf(255.0f * ((float)tid / (float)m)) : 0;
    }
    __syncthreads();

    const int qid = blockIdx.x * ABLK + tid;
    const int rem = qid % QUADS_PER_IMG;
    const int h = rem / (W / 4);
    const int w0 = (rem % (W / 4)) * 4;
    const uint8_t* __restrict__ L = lab + (size_t)b * HW;

    int S0 = 0, S1 = 0, S2 = 0, S3 = 0;
    const int kw5[5] = {1, 4, 6, 4, 1};
#pragma unroll
    for (int i = 0; i < 5; ++i) {
        int r = h + i - 2;                       // reflect-101 row mirror
        r = (r < 0) ? -r : ((r > H - 1) ? (2 * (H - 1) - r) : r);
        const uint8_t* row = L + r * W;
        int q0, q1, q2, q3, q4, q5, q6, q7;      // q at cols w0-2 .. w0+5
        if (w0 >= 4 && w0 <= W - 8) {            // interior: 3 aligned word loads
            uint32_t wa = *(const uint32_t*)(row + w0 - 4);
            uint32_t wb = *(const uint32_t*)(row + w0);
            uint32_t wc = *(const uint32_t*)(row + w0 + 4);
            q0 = qlut[(wa >> 16) & 0xff];
            q1 = qlut[(wa >> 24) & 0xff];
            q2 = qlut[wb & 0xff];
            q3 = qlut[(wb >> 8) & 0xff];
            q4 = qlut[(wb >> 16) & 0xff];
            q5 = qlut[(wb >> 24) & 0xff];
            q6 = qlut[wc & 0xff];
            q7 = qlut[(wc >> 8) & 0xff];
        } else {                                 // edge quads: mirrored byte loads
            int qq[8];
#pragma unroll
            for (int t = 0; t < 8; ++t) {
                int c2 = w0 - 2 + t;
                c2 = (c2 < 0) ? -c2 : ((c2 > W - 1) ? (2 * (W - 1) - c2) : c2);
                qq[t] = qlut[row[c2]];
            }
            q0 = qq[0]; q1 = qq[1]; q2 = qq[2]; q3 = qq[3];
            q4 = qq[4]; q5 = qq[5]; q6 = qq[6]; q7 = qq[7];
        }
        int sh0 = q0 + 4 * q1 + 6 * q2 + 4 * q3 + q4;
        int sh1 = q1 + 4 * q2 + 6 * q3 + 4 * q4 + q5;
        int sh2 = q2 + 4 * q3 + 6 * q4 + 4 * q5 + q6;
        int sh3 = q3 + 4 * q4 + 6 * q5 + 4 * q6 + q7;
        int k = kw5[i];
        S0 += k * sh0; S1 += k * sh1; S2 += k * sh2; S3 += k * sh3;
    }
    uint32_t nib = (S0 > 128 ? 1u : 0u) | (S1 > 128 ? 2u : 0u) |
                   (S2 > 128 ? 4u : 0u) | (S3 > 128 ? 8u : 0u);
    uint32_t wword = nib << ((tid & 7) * 4);
    wword |= __shfl_xor(wword, 1);
    wword |= __shfl_xor(wword, 2);
    wword |= __shfl_xor(wword, 4);
    if ((tid & 7) == 0) mbits[qid >> 3] = wword;  // b*1568 + h*7 + w0/32
}

// ---------------------------------------------------------------------------
// 32x32 bit-tile transpose of a 224x224 bitmask (7x7 tiles) via shfl_xor
// butterflies. src/dst are row-major [224 rows][7 words]; dst gets the
// transposed mask (dst row x = src column x). Stride-7 LDS => conflict-free.
// ---------------------------------------------------------------------------
__device__ __forceinline__ void bit_transpose(const uint32_t* __restrict__ src,
                                              uint32_t* __restrict__ dst,
                                              int tid) {
    const int wave = tid >> 6;
    const int half = (tid >> 5) & 1;
    const int lane5 = tid & 31;
    const uint32_t M1 = 0x55555555u, M2 = 0x33333333u, M4 = 0x0F0F0F0Fu,
                   M8 = 0x00FF00FFu, M16 = 0x0000FFFFu;
#pragma unroll
    for (int t0 = 0; t0 < 49; t0 += 8) {          // 4 waves x 2 tiles per pass
        int t = t0 + wave * 2 + half;
        if (t < 49) {
            int I = t / 7, J = t % 7;             // row-tile, col-word
            uint32_t v = src[(32 * I + lane5) * WPR + J];
            uint32_t o;
            o = __shfl_xor(v, 1);
            v = (lane5 & 1) ? ((v & ~M1) | ((o >> 1) & M1)) : ((v & M1) | ((o & M1) << 1));
            o = __shfl_xor(v, 2);
            v = (lane5 & 2) ? ((v & ~M2) | ((o >> 2) & M2)) : ((v & M2) | ((o & M2) << 2));
            o = __shfl_xor(v, 4);
            v = (lane5 & 4) ? ((v & ~M4) | ((o >> 4) & M4)) : ((v & M4) | ((o & M4) << 4));
            o = __shfl_xor(v, 8);
            v = (lane5 & 8) ? ((v & ~M8) | ((o >> 8) & M8)) : ((v & M8) | ((o & M8) << 8));
            o = __shfl_xor(v, 16);
            v = (lane5 & 16) ? ((v & ~M16) | ((o >> 16) & M16)) : ((v & M16) | ((o & M16) << 16));
            dst[(32 * J + lane5) * WPR + I] = v;
        }
    }
}

// Kogge-Stone masked smear along one 224-bit line (7 words), both directions.
__device__ __forceinline__ uint32_t ks_smear_line(uint32_t* __restrict__ Bw,
                                                  const uint32_t* __restrict__ A,
                                                  int base) {
    uint32_t chg = 0;
    uint32_t carry = 0;                            // carry into bit 0
#pragma unroll
    for (int k = 0; k < WPR; ++k) {
        uint32_t comp = ~A[base + k];
        uint32_t s = Bw[base + k];
        uint32_t f = s | (carry & comp);
        uint32_t m = comp;
        f |= m & (f << 1);  m &= (m << 1);
        f |= m & (f << 2);  m &= (m << 2);
        f |= m & (f << 4);  m &= (m << 4);
        f |= m & (f << 8);  m &= (m << 8);
        f |= m & (f << 16);
        carry = f >> 31;
        chg |= f ^ s;
        Bw[base + k] = f;
    }
    carry = 0;                                     // carry into bit 31
#pragma unroll
    for (int k = WPR - 1; k >= 0; --k) {
        uint32_t comp = ~A[base + k];
        uint32_t s = Bw[base + k];
        uint32_t f = s | ((carry << 31) & comp);
        uint32_t m = comp;
        f |= m & (f >> 1);  m &= (m >> 1);
        f |= m & (f >> 2);  m &= (m >> 2);
        f |= m & (f >> 4);  m &= (m >> 4);
        f |= m & (f >> 8);  m &= (m >> 8);
        f |= m & (f >> 16);
        carry = f & 1u;
        chg |= f ^ s;
        Bw[base + k] = f;
    }
    return chg;
}

// ---------------------------------------------------------------------------
// K3 (fused fill + expand): grid = 16 images x 16 replicas; every replica
// redundantly computes opening + border-flood hole fill in LDS, then writes a
// disjoint 1/16 slice of the output. NEW: empty-seed fast path — if the flood
// seed (~opened & border) is all-zero, the background is provably empty and
// the result is all-True; skip all transposes and the fixpoint loop entirely.
// ---------------------------------------------------------------------------
__global__ __launch_bounds__(256) void k_fillexp(const uint32_t* __restrict__ mbits,
                                                 float* __restrict__ out) {
    const int img = blockIdx.x >> 4;
    const int rep = blockIdx.x & 15;
    const int tid = threadIdx.x;
    __shared__ uint32_t A[IMG_WORDS];    // mask -> opened (row-major)
    __shared__ uint32_t Bw[IMG_WORDS];   // erode temp -> flood state (row-major)
    __shared__ uint32_t AT[IMG_WORDS];   // opened, bit-transposed
    __shared__ uint32_t BT[IMG_WORDS];   // flood state, bit-transposed
    __shared__ int s_changed;
    __shared__ int s_any;

    const uint32_t* src = mbits + img * IMG_WORDS;
    for (int i = tid; i < IMG_WORDS; i += 256) A[i] = src[i];
    if (tid == 0) s_any = 0;
    __syncthreads();

    // erode (out-of-image = True) -> Bw
    for (int i = tid; i < IMG_WORDS; i += 256) {
        int h = i / WPR, k = i % WPR;
        uint32_t cur = A[i];
        uint32_t north = (h > 0) ? A[i - WPR] : 0xFFFFFFFFu;
        uint32_t south = (h < H - 1) ? A[i + WPR] : 0xFFFFFFFFu;
        uint32_t west = (cur << 1) | ((k > 0) ? (A[i - 1] >> 31) : 1u);
        uint32_t east = (cur >> 1) | ((k < WPR - 1) ? (A[i + 1] << 31) : 0x80000000u);
        Bw[i] = cur & north & south & west & east;
    }
    __syncthreads();
    // dilate (out-of-image = False) -> opened into A
    for (int i = tid; i < IMG_WORDS; i += 256) {
        int h = i / WPR, k = i % WPR;
        uint32_t cur = Bw[i];
        uint32_t north = (h > 0) ? Bw[i - WPR] : 0u;
        uint32_t south = (h < H - 1) ? Bw[i + WPR] : 0u;
        uint32_t west = (cur << 1) | ((k > 0) ? (Bw[i - 1] >> 31) : 0u);
        uint32_t east = (cur >> 1) | ((k < WPR - 1) ? (Bw[i + 1] << 31) : 0u);
        A[i] = cur | north | south | west | east;
    }
    __syncthreads();
    // flood seed: Bw = ~opened & border; track whether ANY seed bit is set
    uint32_t myor = 0;
    for (int i = tid; i < IMG_WORDS; i += 256) {
        int h = i / WPR, k = i % WPR;
        uint32_t comp = ~A[i];
        uint32_t border = (h == 0 || h == H - 1)
                              ? 0xFFFFFFFFu
                              : (((k == 0) ? 1u : 0u) | ((k == WPR - 1) ? 0x80000000u : 0u));
        uint32_t s = comp & border;
        Bw[i] = s;
        myor |= s;
    }
    if (__any(myor != 0) && (tid & 63) == 0) s_any = 1;  // benign same-value race
    __syncthreads();

    if (s_any) {
        bit_transpose(A, AT, tid);                // comp is loop-invariant
        __syncthreads();
        // flood to fixpoint: all smears are 224-thread Kogge-Stone;
        // vertical via transposed copies.
        while (true) {
            if (tid == 0) s_changed = 0;
            __syncthreads();
            if (tid < H) {                        // horizontal (rows)
                if (ks_smear_line(Bw, A, tid * WPR)) s_changed = 1;
            }
            __syncthreads();
            bit_transpose(Bw, BT, tid);
            __syncthreads();
            if (tid < W) {                        // vertical (columns)
                if (ks_smear_line(BT, AT, tid * WPR)) s_changed = 1;
            }
            __syncthreads();
            bit_transpose(BT, Bw, tid);
            __syncthreads();
            if (!s_changed) break;                // uniform after barrier
        }
    }
    // else: seed empty -> bg empty -> fill = all True; Bw already all-zero.

    // expand straight from LDS: replica writes float4s [rep*2352,(rep+1)*2352)
    f4* outq = (f4*)out + (size_t)img * OUT_Q4_PER_IMG;
    for (int oi = rep * OUT_Q4_PER_REP + tid; oi < (rep + 1) * OUT_Q4_PER_REP;
         oi += 256) {
        int remq = oi % QUADS_PER_IMG;            // position within one channel
        int h = remq / (W / 4);
        int wq = remq % (W / 4);
        uint32_t word = ~Bw[h * WPR + (wq >> 3)]; // fg = ~bg
        int sh = (wq & 7) * 4;
        f4 v;
        v.x = ((word >> sh) & 1u) ? 1.0f : 0.0f;
        v.y = ((word >> (sh + 1)) & 1u) ? 1.0f : 0.0f;
        v.z = ((word >> (sh + 2)) & 1u) ? 1.0f : 0.0f;
        v.w = ((word >> (sh + 3)) & 1u) ? 1.0f : 0.0f;
        __builtin_nontemporal_store(v, &outq[oi]);
    }
}

// ---------------------------------------------------------------------------
extern "C" void kernel_launch(void* const* d_in, const int* in_sizes, int n_in,
                              void* d_out, int out_size, void* d_ws, size_t ws_size,
                              hipStream_t stream) {
    const float* in = (const float*)d_in[0];   // (16,37,224,224) float32
    float* out = (float*)d_out;                // (16,3,224,224) float32

    uint8_t* lab = (uint8_t*)d_ws;                                // 802816 B
    int* bmax = (int*)((char*)d_ws + 802816);                     // 3136*4 B
    uint32_t* mbits = (uint32_t*)((char*)d_ws + 815360);          // 100352 B

    k_argmax<<<NB * BLOCKS_PER_IMG, ABLK, 0, stream>>>(in, lab, bmax);
    k_mask<<<NB * BLOCKS_PER_IMG, ABLK, 0, stream>>>(lab, bmax, mbits);
    k_fillexp<<<NB * REPS, 256, 0, stream>>>(mbits, out);
}

// Round 2
// 175.360 us; speedup vs baseline: 1.1337x; 1.0687x over previous
//
#include <hip/hip_runtime.h>
#include <stdint.h>

// Problem constants (input: float32 (16, 37, 224, 224), label = 1)
#define NB 16
#define NC 37
#define H 224
#define W 224
#define HW (H * W)                     // 50176
#define WPR 7                          // 32-bit mask words per row (224 = 7*32)
#define IMG_WORDS (H * WPR)            // 1568
#define QUADS_PER_IMG (HW / 4)         // 12544
#define ABLK 64                        // threads per block for k_argmax/k_mask
#define BLOCKS_PER_IMG (QUADS_PER_IMG / ABLK)  // 196
#define REPS 16                        // fill replicas per image
#define OUT_Q4_PER_IMG (3 * H * (W / 4))       // 37632 float4 per image
#define OUT_Q4_PER_REP (OUT_Q4_PER_IMG / REPS) // 2352

typedef float f4 __attribute__((ext_vector_type(4)));

// ---------------------------------------------------------------------------
// K1: channel argmax (first-max tie-break == jnp.argmax). 64-thread blocks:
// 3136 blocks all co-resident on 256 CUs (no block-scheduling tail on a
// memory-bound kernel). Input is 118.75 MB streamed ONCE with zero reuse ->
// nontemporal loads keep it from thrashing L2 (lab stays resident for K2).
// Block max via pure wave shfl reduce — no LDS, no barriers.
// ---------------------------------------------------------------------------
__global__ __launch_bounds__(64) void k_argmax(const float* __restrict__ in,
                                               uint8_t* __restrict__ lab,
                                               int* __restrict__ bmax) {
    const int qid = blockIdx.x * ABLK + threadIdx.x;
    const int b = blockIdx.x / BLOCKS_PER_IMG;
    const int p = (qid % QUADS_PER_IMG) * 4;
    const f4* base = (const f4*)(in + (size_t)b * NC * HW + p);
    f4 bv = __builtin_nontemporal_load(base);
    int ix = 0, iy = 0, iz = 0, iw = 0;
#pragma unroll
    for (int c = 1; c < NC; c += 4) {
        f4 a0 = __builtin_nontemporal_load(base + (size_t)(c + 0) * (HW / 4));
        f4 a1 = __builtin_nontemporal_load(base + (size_t)(c + 1) * (HW / 4));
        f4 a2 = __builtin_nontemporal_load(base + (size_t)(c + 2) * (HW / 4));
        f4 a3 = __builtin_nontemporal_load(base + (size_t)(c + 3) * (HW / 4));
        if (a0.x > bv.x) { bv.x = a0.x; ix = c; }
        if (a0.y > bv.y) { bv.y = a0.y; iy = c; }
        if (a0.z > bv.z) { bv.z = a0.z; iz = c; }
        if (a0.w > bv.w) { bv.w = a0.w; iw = c; }
        if (a1.x > bv.x) { bv.x = a1.x; ix = c + 1; }
        if (a1.y > bv.y) { bv.y = a1.y; iy = c + 1; }
        if (a1.z > bv.z) { bv.z = a1.z; iz = c + 1; }
        if (a1.w > bv.w) { bv.w = a1.w; iw = c + 1; }
        if (a2.x > bv.x) { bv.x = a2.x; ix = c + 2; }
        if (a2.y > bv.y) { bv.y = a2.y; iy = c + 2; }
        if (a2.z > bv.z) { bv.z = a2.z; iz = c + 2; }
        if (a2.w > bv.w) { bv.w = a2.w; iw = c + 2; }
        if (a3.x > bv.x) { bv.x = a3.x; ix = c + 3; }
        if (a3.y > bv.y) { bv.y = a3.y; iy = c + 3; }
        if (a3.z > bv.z) { bv.z = a3.z; iz = c + 3; }
        if (a3.w > bv.w) { bv.w = a3.w; iw = c + 3; }
    }
    uint32_t packed = (uint32_t)ix | ((uint32_t)iy << 8) |
                      ((uint32_t)iz << 16) | ((uint32_t)iw << 24);
    *(uint32_t*)(lab + (size_t)b * HW + p) = packed;

    int mymax = max(max(ix, iy), max(iz, iw));
#pragma unroll
    for (int off = 32; off; off >>= 1) mymax = max(mymax, __shfl_xor(mymax, off));
    if (threadIdx.x == 0) bmax[blockIdx.x] = mymax;
}

// ---------------------------------------------------------------------------
// K2: quantize (37-entry LUT, bit-identical float op sequence) + exact
// integer 5x5 blur (S = sum k_i k_j q), threshold S >= 129
// (== round-half-even(S/256) > 0). 64-thread blocks; the per-image max is
// reduced from bmax[] entirely in-register (wave reduce), one barrier total.
// ---------------------------------------------------------------------------
__global__ __launch_bounds__(64) void k_mask(const uint8_t* __restrict__ lab,
                                             const int* __restrict__ bmax,
                                             uint32_t* __restrict__ mbits) {
    __shared__ int qlut[NC];
    const int tid = threadIdx.x;
    const int b = blockIdx.x / BLOCKS_PER_IMG;

    int m = 0;
    for (int i = tid; i < BLOCKS_PER_IMG; i += ABLK)
        m = max(m, bmax[b * BLOCKS_PER_IMG + i]);
#pragma unroll
    for (int off = 32; off; off >>= 1) m = max(m, __shfl_xor(m, off));
    if (tid < NC) {
        // identical op order to reference: floor(255.0f * (l / maxv))
        qlut[tid] = (m > 0) ? (int)floorf(255.0f * ((float)tid / (float)m)) : 0;
    }
    __syncthreads();

    const int qid = blockIdx.x * ABLK + tid;
    const int rem = qid % QUADS_PER_IMG;
    const int h = rem / (W / 4);
    const int w0 = (rem % (W / 4)) * 4;
    const uint8_t* __restrict__ L = lab + (size_t)b * HW;

    int S0 = 0, S1 = 0, S2 = 0, S3 = 0;
    const int kw5[5] = {1, 4, 6, 4, 1};
#pragma unroll
    for (int i = 0; i < 5; ++i) {
        int r = h + i - 2;                       // reflect-101 row mirror
        r = (r < 0) ? -r : ((r > H - 1) ? (2 * (H - 1) - r) : r);
        const uint8_t* row = L + r * W;
        int q0, q1, q2, q3, q4, q5, q6, q7;      // q at cols w0-2 .. w0+5
        if (w0 >= 4 && w0 <= W - 8) {            // interior: 3 aligned word loads
            uint32_t wa = *(const uint32_t*)(row + w0 - 4);
            uint32_t wb = *(const uint32_t*)(row + w0);
            uint32_t wc = *(const uint32_t*)(row + w0 + 4);
            q0 = qlut[(wa >> 16) & 0xff];
            q1 = qlut[(wa >> 24) & 0xff];
            q2 = qlut[wb & 0xff];
            q3 = qlut[(wb >> 8) & 0xff];
            q4 = qlut[(wb >> 16) & 0xff];
            q5 = qlut[(wb >> 24) & 0xff];
            q6 = qlut[wc & 0xff];
            q7 = qlut[(wc >> 8) & 0xff];
        } else {                                 // edge quads: mirrored byte loads
            int qq[8];
#pragma unroll
            for (int t = 0; t < 8; ++t) {
                int c2 = w0 - 2 + t;
                c2 = (c2 < 0) ? -c2 : ((c2 > W - 1) ? (2 * (W - 1) - c2) : c2);
                qq[t] = qlut[row[c2]];
            }
            q0 = qq[0]; q1 = qq[1]; q2 = qq[2]; q3 = qq[3];
            q4 = qq[4]; q5 = qq[5]; q6 = qq[6]; q7 = qq[7];
        }
        int sh0 = q0 + 4 * q1 + 6 * q2 + 4 * q3 + q4;
        int sh1 = q1 + 4 * q2 + 6 * q3 + 4 * q4 + q5;
        int sh2 = q2 + 4 * q3 + 6 * q4 + 4 * q5 + q6;
        int sh3 = q3 + 4 * q4 + 6 * q5 + 4 * q6 + q7;
        int k = kw5[i];
        S0 += k * sh0; S1 += k * sh1; S2 += k * sh2; S3 += k * sh3;
    }
    uint32_t nib = (S0 > 128 ? 1u : 0u) | (S1 > 128 ? 2u : 0u) |
                   (S2 > 128 ? 4u : 0u) | (S3 > 128 ? 8u : 0u);
    uint32_t wword = nib << ((tid & 7) * 4);
    wword |= __shfl_xor(wword, 1);
    wword |= __shfl_xor(wword, 2);
    wword |= __shfl_xor(wword, 4);
    if ((tid & 7) == 0) mbits[qid >> 3] = wword;  // b*1568 + h*7 + w0/32
}

// ---------------------------------------------------------------------------
// 32x32 bit-tile transpose of a 224x224 bitmask (7x7 tiles) via shfl_xor
// butterflies. src/dst are row-major [224 rows][7 words]; dst gets the
// transposed mask (dst row x = src column x). Stride-7 LDS => conflict-free.
// ---------------------------------------------------------------------------
__device__ __forceinline__ void bit_transpose(const uint32_t* __restrict__ src,
                                              uint32_t* __restrict__ dst,
                                              int tid) {
    const int wave = tid >> 6;
    const int half = (tid >> 5) & 1;
    const int lane5 = tid & 31;
    const uint32_t M1 = 0x55555555u, M2 = 0x33333333u, M4 = 0x0F0F0F0Fu,
                   M8 = 0x00FF00FFu, M16 = 0x0000FFFFu;
#pragma unroll
    for (int t0 = 0; t0 < 49; t0 += 8) {          // 4 waves x 2 tiles per pass
        int t = t0 + wave * 2 + half;
        if (t < 49) {
            int I = t / 7, J = t % 7;             // row-tile, col-word
            uint32_t v = src[(32 * I + lane5) * WPR + J];
            uint32_t o;
            o = __shfl_xor(v, 1);
            v = (lane5 & 1) ? ((v & ~M1) | ((o >> 1) & M1)) : ((v & M1) | ((o & M1) << 1));
            o = __shfl_xor(v, 2);
            v = (lane5 & 2) ? ((v & ~M2) | ((o >> 2) & M2)) : ((v & M2) | ((o & M2) << 2));
            o = __shfl_xor(v, 4);
            v = (lane5 & 4) ? ((v & ~M4) | ((o >> 4) & M4)) : ((v & M4) | ((o & M4) << 4));
            o = __shfl_xor(v, 8);
            v = (lane5 & 8) ? ((v & ~M8) | ((o >> 8) & M8)) : ((v & M8) | ((o & M8) << 8));
            o = __shfl_xor(v, 16);
            v = (lane5 & 16) ? ((v & ~M16) | ((o >> 16) & M16)) : ((v & M16) | ((o & M16) << 16));
            dst[(32 * J + lane5) * WPR + I] = v;
        }
    }
}

// Kogge-Stone masked smear along one 224-bit line (7 words), both directions.
__device__ __forceinline__ uint32_t ks_smear_line(uint32_t* __restrict__ Bw,
                                                  const uint32_t* __restrict__ A,
                                                  int base) {
    uint32_t chg = 0;
    uint32_t carry = 0;                            // carry into bit 0
#pragma unroll
    for (int k = 0; k < WPR; ++k) {
        uint32_t comp = ~A[base + k];
        uint32_t s = Bw[base + k];
        uint32_t f = s | (carry & comp);
        uint32_t m = comp;
        f |= m & (f << 1);  m &= (m << 1);
        f |= m & (f << 2);  m &= (m << 2);
        f |= m & (f << 4);  m &= (m << 4);
        f |= m & (f << 8);  m &= (m << 8);
        f |= m & (f << 16);
        carry = f >> 31;
        chg |= f ^ s;
        Bw[base + k] = f;
    }
    carry = 0;                                     // carry into bit 31
#pragma unroll
    for (int k = WPR - 1; k >= 0; --k) {
        uint32_t comp = ~A[base + k];
        uint32_t s = Bw[base + k];
        uint32_t f = s | ((carry << 31) & comp);
        uint32_t m = comp;
        f |= m & (f >> 1);  m &= (m >> 1);
        f |= m & (f >> 2);  m &= (m >> 2);
        f |= m & (f >> 4);  m &= (m >> 4);
        f |= m & (f >> 8);  m &= (m >> 8);
        f |= m & (f >> 16);
        carry = f & 1u;
        chg |= f ^ s;
        Bw[base + k] = f;
    }
    return chg;
}

// ---------------------------------------------------------------------------
// K3 (fused fill + expand): grid = 16 images x 16 replicas; every replica
// redundantly computes opening + border-flood hole fill in LDS, then writes a
// disjoint 1/16 slice of the output. Empty-seed fast path: if the flood seed
// (~opened & border) is all-zero, the background is provably empty -> result
// is all-True; skip the transposes/fixpoint AND write constant 1.0f quads
// (no LDS reads / bit tests in the expand loop).
// ---------------------------------------------------------------------------
__global__ __launch_bounds__(256) void k_fillexp(const uint32_t* __restrict__ mbits,
                                                 float* __restrict__ out) {
    const int img = blockIdx.x >> 4;
    const int rep = blockIdx.x & 15;
    const int tid = threadIdx.x;
    __shared__ uint32_t A[IMG_WORDS];    // mask -> opened (row-major)
    __shared__ uint32_t Bw[IMG_WORDS];   // erode temp -> flood state (row-major)
    __shared__ uint32_t AT[IMG_WORDS];   // opened, bit-transposed
    __shared__ uint32_t BT[IMG_WORDS];   // flood state, bit-transposed
    __shared__ int s_changed;
    __shared__ int s_any;

    const uint32_t* src = mbits + img * IMG_WORDS;
    for (int i = tid; i < IMG_WORDS; i += 256) A[i] = src[i];
    if (tid == 0) s_any = 0;
    __syncthreads();

    // erode (out-of-image = True) -> Bw
    for (int i = tid; i < IMG_WORDS; i += 256) {
        int h = i / WPR, k = i % WPR;
        uint32_t cur = A[i];
        uint32_t north = (h > 0) ? A[i - WPR] : 0xFFFFFFFFu;
        uint32_t south = (h < H - 1) ? A[i + WPR] : 0xFFFFFFFFu;
        uint32_t west = (cur << 1) | ((k > 0) ? (A[i - 1] >> 31) : 1u);
        uint32_t east = (cur >> 1) | ((k < WPR - 1) ? (A[i + 1] << 31) : 0x80000000u);
        Bw[i] = cur & north & south & west & east;
    }
    __syncthreads();
    // dilate (out-of-image = False) -> opened into A
    for (int i = tid; i < IMG_WORDS; i += 256) {
        int h = i / WPR, k = i % WPR;
        uint32_t cur = Bw[i];
        uint32_t north = (h > 0) ? Bw[i - WPR] : 0u;
        uint32_t south = (h < H - 1) ? Bw[i + WPR] : 0u;
        uint32_t west = (cur << 1) | ((k > 0) ? (Bw[i - 1] >> 31) : 0u);
        uint32_t east = (cur >> 1) | ((k < WPR - 1) ? (Bw[i + 1] << 31) : 0u);
        A[i] = cur | north | south | west | east;
    }
    __syncthreads();
    // flood seed: Bw = ~opened & border; track whether ANY seed bit is set
    uint32_t myor = 0;
    for (int i = tid; i < IMG_WORDS; i += 256) {
        int h = i / WPR, k = i % WPR;
        uint32_t comp = ~A[i];
        uint32_t border = (h == 0 || h == H - 1)
                              ? 0xFFFFFFFFu
                              : (((k == 0) ? 1u : 0u) | ((k == WPR - 1) ? 0x80000000u : 0u));
        uint32_t s = comp & border;
        Bw[i] = s;
        myor |= s;
    }
    if (__any(myor != 0) && (tid & 63) == 0) s_any = 1;  // benign same-value race
    __syncthreads();

    f4* outq = (f4*)out + (size_t)img * OUT_Q4_PER_IMG;

    if (!s_any) {
        // seed empty -> bg empty -> fill = all True -> out slice is all 1.0f
        const f4 ones = {1.0f, 1.0f, 1.0f, 1.0f};
        for (int oi = rep * OUT_Q4_PER_REP + tid;
             oi < (rep + 1) * OUT_Q4_PER_REP; oi += 256)
            __builtin_nontemporal_store(ones, &outq[oi]);
        return;
    }

    bit_transpose(A, AT, tid);                    // comp is loop-invariant
    __syncthreads();
    // flood to fixpoint: all smears are 224-thread Kogge-Stone;
    // vertical via transposed copies.
    while (true) {
        if (tid == 0) s_changed = 0;
        __syncthreads();
        if (tid < H) {                            // horizontal (rows)
            if (ks_smear_line(Bw, A, tid * WPR)) s_changed = 1;
        }
        __syncthreads();
        bit_transpose(Bw, BT, tid);
        __syncthreads();
        if (tid < W) {                            // vertical (columns)
            if (ks_smear_line(BT, AT, tid * WPR)) s_changed = 1;
        }
        __syncthreads();
        bit_transpose(BT, Bw, tid);
        __syncthreads();
        if (!s_changed) break;                    // uniform after barrier
    }

    // expand straight from LDS: replica writes float4s [rep*2352,(rep+1)*2352)
    for (int oi = rep * OUT_Q4_PER_REP + tid; oi < (rep + 1) * OUT_Q4_PER_REP;
         oi += 256) {
        int remq = oi % QUADS_PER_IMG;            // position within one channel
        int h = remq / (W / 4);
        int wq = remq % (W / 4);
        uint32_t word = ~Bw[h * WPR + (wq >> 3)]; // fg = ~bg
        int sh = (wq & 7) * 4;
        f4 v;
        v.x = ((word >> sh) & 1u) ? 1.0f : 0.0f;
        v.y = ((word >> (sh + 1)) & 1u) ? 1.0f : 0.0f;
        v.z = ((word >> (sh + 2)) & 1u) ? 1.0f : 0.0f;
        v.w = ((word >> (sh + 3)) & 1u) ? 1.0f : 0.0f;
        __builtin_nontemporal_store(v, &outq[oi]);
    }
}

// ---------------------------------------------------------------------------
extern "C" void kernel_launch(void* const* d_in, const int* in_sizes, int n_in,
                              void* d_out, int out_size, void* d_ws, size_t ws_size,
                              hipStream_t stream) {
    const float* in = (const float*)d_in[0];   // (16,37,224,224) float32
    float* out = (float*)d_out;                // (16,3,224,224) float32

    uint8_t* lab = (uint8_t*)d_ws;                                // 802816 B
    int* bmax = (int*)((char*)d_ws + 802816);                     // 3136*4 B
    uint32_t* mbits = (uint32_t*)((char*)d_ws + 815360);          // 100352 B

    k_argmax<<<NB * BLOCKS_PER_IMG, ABLK, 0, stream>>>(in, lab, bmax);
    k_mask<<<NB * BLOCKS_PER_IMG, ABLK, 0, stream>>>(lab, bmax, mbits);
    k_fillexp<<<NB * REPS, 256, 0, stream>>>(mbits, out);
}